// Round 15
// baseline (90.292 us; speedup 1.0000x reference)
//
#include <hip/hip_runtime.h>

#define B_ROWS 16384
#define I_DIM  512
#define O_DIM  64
#define NFEAT  8          // 2*K fourier features per x element
#define TROWS  64         // b-rows per block (R12 geometry: 1 block/CU)
#define XPAD   516        // LDS row stride in floats; 516%32==4 -> column reads 2-way (free)
// W2t: [I_DIM][O_DIM][NFEAT] f16  (512 KB)   at d_ws + 0
// cst: [O_DIM] f32                           at d_ws + W2_BYTES
#define W2_BYTES ((size_t)I_DIM * O_DIM * NFEAT * 2)

typedef _Float16 f16x8 __attribute__((ext_vector_type(8)));
typedef float    f32x4 __attribute__((ext_vector_type(4)));

// ---------------- fused prep: W2 + const, one launch ----------------
__global__ __launch_bounds__(256) void prep(const float* __restrict__ w,
                                            const float* __restrict__ coef,
                                            _Float16* __restrict__ w2,
                                            float* __restrict__ cst) {
    const int o = blockIdx.x;
    const int t = threadIdx.x;
    float csum = 0.f;
#pragma unroll
    for (int ii = 0; ii < 2; ++ii) {
        const int i   = ii * 256 + t;
        const int idx = o * I_DIM + i;
        const float wv = w[idx];
        const float* cp = coef + (size_t)idx * 9;
        csum += wv * cp[0];
        f16x8 v;
#pragma unroll
        for (int f = 0; f < 8; ++f) v[f] = (_Float16)(wv * cp[f + 1]);   // RTN
        *reinterpret_cast<f16x8*>(w2 + ((size_t)(i * 64 + o)) * 8) = v;
    }
#pragma unroll
    for (int off = 32; off; off >>= 1) csum += __shfl_down(csum, off, 64);
    __shared__ float ps[4];
    if ((t & 63) == 0) ps[t >> 6] = csum;
    __syncthreads();
    if (t == 0) cst[o] = ps[0] + ps[1] + ps[2] + ps[3];
}

// ---------------- main: out[64 rows x 64 cols] per block ----------------
// R12's measured-good geometry (64 rows, XPAD, 1 block/CU, no occupancy
// attribute -- R11 proved forced-occupancy can spill even with headroom).
// Deltas vs R12: HW trig (v_fract+v_sin/v_cos on revolutions, exact by
// periodicity) and fused prep. Discriminator round: if dur stays ~90 the
// timed window is harness-floor-dominated; if main was attr/traffic
// inflated, dur -> 60-75.
__global__ __launch_bounds__(512)
void fourier_main(const float* __restrict__ x,
                  const _Float16* __restrict__ w2,
                  const float* __restrict__ cst,
                  float* __restrict__ out) {
    __shared__ __align__(16) float xs[TROWS][XPAD];                  // 132096 B
    float (*red)[TROWS][65] = reinterpret_cast<float(*)[TROWS][65]>(&xs[0][0]);

    const int tid   = threadIdx.x;
    const int wave  = tid >> 6;
    const int lane  = tid & 63;
    const int col16 = lane & 15;   // A-row within tile / B,D column
    const int ig    = lane >> 4;   // i sub-offset 0..3 (k-chunk of fragment)
    const int rbase = blockIdx.x * TROWS;
    const int i0    = wave * 64;   // this wave's K-slice (64 i's = 512 k's)

    // ---- phase 1: stage x (64 rows x 512 f32 = 128KB), coalesced ----
    {
        const float4* xg = reinterpret_cast<const float4*>(x + (size_t)rbase * I_DIM);
#pragma unroll
        for (int j = 0; j < 16; ++j) {
            int f4   = j * 512 + tid;         // wave reads 1KB contiguous per j
            float4 v = xg[f4];
            *reinterpret_cast<float4*>(&xs[f4 >> 7][(f4 & 127) << 2]) = v;
        }
    }
    __syncthreads();

    // ---- phase 2: MFMA main loop (s outer, m inner) ----
    f32x4 acc[4][4] = {};          // [mtile][ntile], f32 accum
    const f16x8* __restrict__ bbase = reinterpret_cast<const f16x8*>(w2);
    const float RINV = 0.15915494309189535f;   // 1/(2*pi)

    f16x8 bf[4], bn[4];
    {
        const int i = i0 + ig;
#pragma unroll
        for (int n = 0; n < 4; ++n) bf[n] = bbase[i * 64 + n * 16 + col16];
    }

    for (int s = 0; s < 16; ++s) {
        const int i = i0 + s * 4 + ig;

        if (s < 15) {
            const int i2 = i + 4;
#pragma unroll
            for (int n = 0; n < 4; ++n) bn[n] = bbase[i2 * 64 + n * 16 + col16];
        }

        float xv[4];
#pragma unroll
        for (int m = 0; m < 4; ++m) xv[m] = xs[m * 16 + col16][i];  // 2-way: free

#pragma unroll
        for (int m = 0; m < 4; ++m) {
            // sin(x), cos(x) via trans pipe (input in revolutions per ISA)
            const float r  = __builtin_amdgcn_fractf(xv[m] * RINV);
            const float s1 = __builtin_amdgcn_sinf(r);
            const float c1 = __builtin_amdgcn_cosf(r);
            const float tc = 2.f * c1;
            const float s2 = tc * s1;          // sin2
            const float c2 = tc * c1 - 1.f;    // cos2
            const float s3 = tc * s2 - s1;     // sin3
            const float c3 = tc * c2 - c1;     // cos3
            const float s4 = tc * s3 - s2;     // sin4
            const float c4 = tc * c3 - c2;     // cos4
            f16x8 af;
            af[0] = (_Float16)s1; af[1] = (_Float16)c1;   // RTN casts
            af[2] = (_Float16)s2; af[3] = (_Float16)c2;
            af[4] = (_Float16)s3; af[5] = (_Float16)c3;
            af[6] = (_Float16)s4; af[7] = (_Float16)c4;
#pragma unroll
            for (int n = 0; n < 4; ++n)
                acc[m][n] = __builtin_amdgcn_mfma_f32_16x16x32_f16(af, bf[n], acc[m][n], 0, 0, 0);
        }

#pragma unroll
        for (int n = 0; n < 4; ++n) bf[n] = bn[n];
    }

    // ---- phase 3: 8 K-slices -> 4 LDS slices -> sum + const -> out ----
    __syncthreads();               // xs dead; safe to overwrite as red
    if (wave < 4) {
#pragma unroll
        for (int m = 0; m < 4; ++m)
#pragma unroll
            for (int n = 0; n < 4; ++n)
#pragma unroll
                for (int q = 0; q < 4; ++q)
                    red[wave][m * 16 + ig * 4 + q][n * 16 + col16] = acc[m][n][q];
    }
    __syncthreads();
    if (wave >= 4) {
#pragma unroll
        for (int m = 0; m < 4; ++m)
#pragma unroll
            for (int n = 0; n < 4; ++n)
#pragma unroll
                for (int q = 0; q < 4; ++q)
                    red[wave - 4][m * 16 + ig * 4 + q][n * 16 + col16] += acc[m][n][q];
    }
    __syncthreads();

    const float cv = cst[lane];            // out column = lane
#pragma unroll
    for (int j = 0; j < 8; ++j) {
        const int r = wave + 8 * j;        // rows 0..63
        float v = cv + red[0][r][lane] + red[1][r][lane] + red[2][r][lane] + red[3][r][lane];
        out[(size_t)(rbase + r) * 64 + lane] = v;   // wave writes 256B contiguous
    }
}

extern "C" void kernel_launch(void* const* d_in, const int* in_sizes, int n_in,
                              void* d_out, int out_size, void* d_ws, size_t ws_size,
                              hipStream_t stream) {
    const float* x    = (const float*)d_in[0];
    const float* w    = (const float*)d_in[1];
    const float* coef = (const float*)d_in[2];
    _Float16* w2  = (_Float16*)d_ws;
    float*    cst = (float*)((char*)d_ws + W2_BYTES);
    float*    out = (float*)d_out;

    hipLaunchKernelGGL(prep, dim3(O_DIM), dim3(256), 0, stream, w, coef, w2, cst);
    hipLaunchKernelGGL(fourier_main, dim3(B_ROWS / TROWS), dim3(512), 0, stream, x, w2, cst, out);
}